// Round 13
// baseline (321.428 us; speedup 1.0000x reference)
//
#include <hip/hip_runtime.h>
#include <hip/hip_bf16.h>

// AutoInt fused: embedding gather -> 2x MHSA (32 fields, 4 heads x 32) -> logit.
// R13 = R12 (2 samples/wave, shared W frags, dual MFMA chains) +
//   (a) packed bf16 converts via __float22bfloat162_rn (v_cvt_pk_bf16_f32),
//   (b) sequential per-sample PV/sums epilogue (kills spill, lowers AGPR peak).

#define NSAMP 8192
#define S_Y1 72    // layer1 input stride (shorts)
#define S_Y2 136   // layer2 input stride (shorts)
#define S_T 36     // 32x32 tile stride (shorts)

typedef __attribute__((ext_vector_type(8))) short bf8_t;   // 8 bf16 (4 VGPRs)
typedef __attribute__((ext_vector_type(16))) float f16v;   // 32x32 C/D

__device__ __forceinline__ unsigned pk2u(float a, float b) {
  __hip_bfloat162 h = __float22bfloat162_rn(make_float2(a, b));  // RNE, packed
  unsigned u; __builtin_memcpy(&u, &h, 4); return u;             // low16 = a
}
__device__ __forceinline__ short f2bf(float f) {
  unsigned u = __float_as_uint(f);
  u += 0x7fffu + ((u >> 16) & 1u);   // RNE (scalar fallback)
  return (short)(u >> 16);
}
__device__ __forceinline__ float bf2f(short s) {
  return __uint_as_float(((unsigned)(unsigned short)s) << 16);
}
__device__ __forceinline__ f16v mfma32(bf8_t a, bf8_t b, f16v c) {
  return __builtin_amdgcn_mfma_f32_32x32x16_bf16(a, b, c, 0, 0, 0);
}

// Two samples' 32x32 proj tiles sharing one set of W fragments.
template<int D>
__device__ __forceinline__ void proj2(const bf8_t (&af)[2][D / 16],
                                      const short* __restrict__ W,
                                      const float* __restrict__ bias,
                                      int n0, int col, int h2, f16v (&o)[2]) {
  float bb = bias[n0 + col];
#pragma unroll
  for (int i = 0; i < 16; ++i) { o[0][i] = bb; o[1][i] = bb; }
#pragma unroll
  for (int kc = 0; kc < D / 16; ++kc) {
    bf8_t w = *(const bf8_t*)&W[(n0 + col) * D + kc * 16 + h2 * 8];
    o[0] = mfma32(af[0][kc], w, o[0]);
    o[1] = mfma32(af[1][kc], w, o[1]);
  }
}

// One attention layer for this wave's head, BOTH samples (R12 structure).
template<int D_IN, int S_IN, bool FUSE>
__device__ void attn_layer(const short* yIn0, const short* yIn1,
                           short* yOut0, short* yOut1,
                           const short* __restrict__ Wq, const short* __restrict__ Wk,
                           const short* __restrict__ Wv, const short* __restrict__ Wr,
                           const float* __restrict__ bq, const float* __restrict__ bk,
                           const float* __restrict__ bvp, const float* __restrict__ br,
                           short* bQ0, short* bK0, short* bQ1, short* bK1,
                           const short* __restrict__ lwT,
                           int n0, int col, int h2, float (&pp)[2]) {
  constexpr int KS = D_IN / 16;
  const short* yIn[2] = {yIn0, yIn1};
  short* bQ[2] = {bQ0, bQ1};
  short* bK[2] = {bK0, bK1};

  // A-fragments for both samples
  bf8_t af[2][KS];
#pragma unroll
  for (int sp = 0; sp < 2; ++sp)
#pragma unroll
    for (int kc = 0; kc < KS; ++kc)
      af[sp][kc] = *(const bf8_t*)&yIn[sp][col * S_IN + kc * 16 + h2 * 8];
  __syncthreads();   // yIn overlays dead; tile regions writable

  f16v acc[2];

  // ---- Q -> bQ row-major (paired packed converts; rows r,r+1)
  proj2<D_IN>(af, Wq, bq, n0, col, h2, acc);
#pragma unroll
  for (int sp = 0; sp < 2; ++sp)
#pragma unroll
    for (int reg = 0; reg < 16; reg += 2) {
      int row = (reg & 3) + 8 * (reg >> 2) + 4 * h2;
      unsigned u = pk2u(acc[sp][reg], acc[sp][reg + 1]);
      bQ[sp][row * S_T + col] = (short)u;
      bQ[sp][(row + 1) * S_T + col] = (short)(u >> 16);
    }

  // ---- K -> bK row-major
  proj2<D_IN>(af, Wk, bk, n0, col, h2, acc);
#pragma unroll
  for (int sp = 0; sp < 2; ++sp)
#pragma unroll
    for (int reg = 0; reg < 16; reg += 2) {
      int row = (reg & 3) + 8 * (reg >> 2) + 4 * h2;
      unsigned u = pk2u(acc[sp][reg], acc[sp][reg + 1]);
      bK[sp][row * S_T + col] = (short)u;
      bK[sp][(row + 1) * S_T + col] = (short)(u >> 16);
    }

  // ---- Res -> registers (C-layout, aligned with PV output)
  f16v res[2];
  proj2<D_IN>(af, Wr, br, n0, col, h2, res);

  // ---- scores = Q K^T; e = exp(z) -> bQ (unnormalized; scores O(1))
#pragma unroll
  for (int sp = 0; sp < 2; ++sp) {
    f16v z;
#pragma unroll
    for (int i = 0; i < 16; ++i) z[i] = 0.f;
#pragma unroll
    for (int kc = 0; kc < 2; ++kc) {
      bf8_t qa = *(const bf8_t*)&bQ[sp][col * S_T + kc * 16 + h2 * 8];
      bf8_t kb = *(const bf8_t*)&bK[sp][col * S_T + kc * 16 + h2 * 8];
      z = mfma32(qa, kb, z);
    }
#pragma unroll
    for (int reg = 0; reg < 16; reg += 2) {
      int row = (reg & 3) + 8 * (reg >> 2) + 4 * h2;
      unsigned u = pk2u(__expf(z[reg]), __expf(z[reg + 1]));
      bQ[sp][row * S_T + col] = (short)u;
      bQ[sp][(row + 1) * S_T + col] = (short)(u >> 16);
    }
  }

  // ---- V -> bK transposed (both samples); packed 8B stores
  proj2<D_IN>(af, Wv, bvp, n0, col, h2, acc);
#pragma unroll
  for (int sp = 0; sp < 2; ++sp)
#pragma unroll
    for (int g = 0; g < 4; ++g) {
      uint2 w;
      w.x = pk2u(acc[sp][g * 4 + 0], acc[sp][g * 4 + 1]);
      w.y = pk2u(acc[sp][g * 4 + 2], acc[sp][g * 4 + 3]);
      *(uint2*)&bK[sp][col * S_T + 8 * g + 4 * h2] = w;
    }

  // ---- PV + row-sums, SEQUENTIAL per sample (one pv/sums live at a time)
  const short onebf = (short)0x3F80;
  bf8_t ones = {onebf, onebf, onebf, onebf, onebf, onebf, onebf, onebf};

  if (FUSE) {
    short4 l4[4];
#pragma unroll
    for (int g = 0; g < 4; ++g)
      l4[g] = *(const short4*)&lwT[(n0 + col) * 32 + 8 * g + 4 * h2];
#pragma unroll
    for (int sp = 0; sp < 2; ++sp) {
      f16v pv, sums;
#pragma unroll
      for (int i = 0; i < 16; ++i) { pv[i] = 0.f; sums[i] = 0.f; }
#pragma unroll
      for (int kc = 0; kc < 2; ++kc) {
        bf8_t pa = *(const bf8_t*)&bQ[sp][col * S_T + kc * 16 + h2 * 8];
        bf8_t vb = *(const bf8_t*)&bK[sp][col * S_T + kc * 16 + h2 * 8];
        pv = mfma32(pa, vb, pv);
        sums = mfma32(pa, ones, sums);
      }
#pragma unroll
      for (int g = 0; g < 4; ++g)
#pragma unroll
        for (int r = 0; r < 4; ++r) {
          int reg = g * 4 + r;
          float lw = bf2f((r == 0) ? l4[g].x : (r == 1) ? l4[g].y
                          : (r == 2) ? l4[g].z : l4[g].w);
          pp[sp] += fmaxf(fmaf(pv[reg], 1.f / sums[reg], res[sp][reg]), 0.f) * lw;
        }
    }
  } else {
    unsigned opk[2][8];
#pragma unroll
    for (int sp = 0; sp < 2; ++sp) {
      f16v pv, sums;
#pragma unroll
      for (int i = 0; i < 16; ++i) { pv[i] = 0.f; sums[i] = 0.f; }
#pragma unroll
      for (int kc = 0; kc < 2; ++kc) {
        bf8_t pa = *(const bf8_t*)&bQ[sp][col * S_T + kc * 16 + h2 * 8];
        bf8_t vb = *(const bf8_t*)&bK[sp][col * S_T + kc * 16 + h2 * 8];
        pv = mfma32(pa, vb, pv);
        sums = mfma32(pa, ones, sums);
      }
#pragma unroll
      for (int reg = 0; reg < 16; reg += 2) {
        float o0 = fmaxf(fmaf(pv[reg], 1.f / sums[reg], res[sp][reg]), 0.f);
        float o1 = fmaxf(fmaf(pv[reg + 1], 1.f / sums[reg + 1], res[sp][reg + 1]), 0.f);
        opk[sp][reg >> 1] = pk2u(o0, o1);
      }
    }
    __syncthreads();   // all waves done reading tiles; regions writable as yOut
    short* yOut[2] = {yOut0, yOut1};
#pragma unroll
    for (int sp = 0; sp < 2; ++sp)
#pragma unroll
      for (int reg = 0; reg < 16; reg += 2) {
        int row = (reg & 3) + 8 * (reg >> 2) + 4 * h2;
        unsigned u = opk[sp][reg >> 1];
        yOut[sp][row * S_Y2 + n0 + col] = (short)u;
        yOut[sp][(row + 1) * S_Y2 + n0 + col] = (short)(u >> 16);
      }
  }
}

__global__ __launch_bounds__(256, 3) void autoint_main(
    const int* __restrict__ onehot_i, const float* __restrict__ onehot_x,
    const int* __restrict__ mh_i, const float* __restrict__ mh_x,
    const float* __restrict__ ctns, const float* __restrict__ xx,
    const float* __restrict__ xy,
    const float* __restrict__ bq1, const float* __restrict__ bk1,
    const float* __restrict__ bv1, const float* __restrict__ br1,
    const float* __restrict__ bq2, const float* __restrict__ bk2,
    const float* __restrict__ bv2, const float* __restrict__ br2,
    const float* __restrict__ logitb, const short* __restrict__ wbf,
    float* __restrict__ out) {
  // Per-sample 18432B region (8 head-tiles) hosting y1 (4608B) / y2 (8704B)
  // overlays at its base, lifetimes fenced by barriers. Two samples/block.
  __shared__ __align__(16) short scr[2][9216];
  __shared__ float red[4][2];

  const int t = threadIdx.x;
  const int head = t >> 6;
  const int lane = t & 63;
  const int col = lane & 31;
  const int h2 = lane >> 5;
  const int n0 = head * 32;
  const int s0 = blockIdx.x * 2;

  short* bQ0 = &scr[0][(head * 2 + 0) * 1152];
  short* bK0 = &scr[0][(head * 2 + 1) * 1152];
  short* bQ1 = &scr[1][(head * 2 + 0) * 1152];
  short* bK1 = &scr[1][(head * 2 + 1) * 1152];

  // ---- embedding build: both samples' y1, all 256 threads each
#pragma unroll
  for (int se = 0; se < 2; ++se) {
    const int sg = s0 + se;
    short* yA = &scr[se][0];
    for (int idx = t; idx < 320; idx += 256) {     // 20 onehot x 16 float4
      int f = idx >> 4, e4 = idx & 15;
      int row = onehot_i[sg * 20 + f];
      float xw = onehot_x[sg * 20 + f];
      float4 xv = *(const float4*)&xx[row * 64 + e4 * 4];
      uint2 w; w.x = pk2u(xv.x * xw, xv.y * xw); w.y = pk2u(xv.z * xw, xv.w * xw);
      *(uint2*)&yA[f * S_Y1 + e4 * 4] = w;
    }
    {                                               // 2 multihot x 16 float4, 8-way k-split
      int slot = t >> 3, ks = t & 7;
      int j = slot >> 4, e4 = slot & 15;
      const int* ip = &mh_i[(j * NSAMP + sg) * 50];
      const float* xp = &mh_x[(j * NSAMP + sg) * 50];
      float a0 = 0.f, a1 = 0.f, a2 = 0.f, a3 = 0.f;
      for (int k = ks; k < 50; k += 8) {
        float4 xv = *(const float4*)&xx[ip[k] * 64 + e4 * 4];
        float w = xp[k];
        a0 += xv.x * w; a1 += xv.y * w; a2 += xv.z * w; a3 += xv.w * w;
      }
#pragma unroll
      for (int d = 1; d < 8; d <<= 1) {
        a0 += __shfl_xor(a0, d); a1 += __shfl_xor(a1, d);
        a2 += __shfl_xor(a2, d); a3 += __shfl_xor(a3, d);
      }
      if (ks == 0) {
        uint2 w; w.x = pk2u(a0, a1); w.y = pk2u(a2, a3);
        *(uint2*)&yA[(20 + j) * S_Y1 + e4 * 4] = w;
      }
    }
    if (t < 160) {                                  // 10 ctns x 16 float4
      int ci = t >> 4, e4 = t & 15;
      float cv = ctns[sg * 10 + ci];
      float4 xv = *(const float4*)&xy[ci * 64 + e4 * 4];
      uint2 w; w.x = pk2u(cv * xv.x, cv * xv.y); w.y = pk2u(cv * xv.z, cv * xv.w);
      *(uint2*)&yA[(22 + ci) * S_Y1 + e4 * 4] = w;
    }
  }
  __syncthreads();

  float pp[2] = {0.f, 0.f};
  attn_layer<64, S_Y1, false>(&scr[0][0], &scr[1][0], &scr[0][0], &scr[1][0],
      wbf + 0, wbf + 8192, wbf + 16384, wbf + 24576,
      bq1, bk1, bv1, br1, bQ0, bK0, bQ1, bK1, nullptr, n0, col, h2, pp);
  __syncthreads();   // y2 fully written before layer2 frag load
  attn_layer<128, S_Y2, true>(&scr[0][0], &scr[1][0], nullptr, nullptr,
      wbf + 32768, wbf + 49152, wbf + 65536, wbf + 81920,
      bq2, bk2, bv2, br2, bQ0, bK0, bQ1, bK1, wbf + 98304, n0, col, h2, pp);

  // ---- logit partials: wave-reduce each sample, combine heads
#pragma unroll
  for (int off = 32; off > 0; off >>= 1) {
    pp[0] += __shfl_xor(pp[0], off);
    pp[1] += __shfl_xor(pp[1], off);
  }
  if (lane == 0) { red[head][0] = pp[0]; red[head][1] = pp[1]; }
  __syncthreads();
  if (t < 2) {
    float zz = red[0][t] + red[1][t] + red[2][t] + red[3][t] + logitb[0];
    out[s0 + t] = 1.f / (1.f + __expf(-zz));
  }
}

// fp32 -> bf16 weight conversion into ws:
// [0)QW1 [8192)KW1 [16384)VW1 [24576)RW1 [32768)QW2 [49152)KW2 [65536)VW2
// [81920)RW2 [98304)logitW TRANSPOSED [128][32]
__global__ void convert_w(const float* __restrict__ qw1, const float* __restrict__ kw1,
                          const float* __restrict__ vw1, const float* __restrict__ rw1,
                          const float* __restrict__ qw2, const float* __restrict__ kw2,
                          const float* __restrict__ vw2, const float* __restrict__ rw2,
                          const float* __restrict__ lw, short* __restrict__ outw) {
  int i = blockIdx.x * 256 + threadIdx.x;
  if (i >= 102400) return;
  float v;
  if (i < 32768) {
    int tsel = i >> 13, j = i & 8191;
    const float* src = tsel == 0 ? qw1 : tsel == 1 ? kw1 : tsel == 2 ? vw1 : rw1;
    v = src[j];
  } else if (i < 98304) {
    int k = i - 32768;
    int tsel = k >> 14, j = k & 16383;
    const float* src = tsel == 0 ? qw2 : tsel == 1 ? kw2 : tsel == 2 ? vw2 : rw2;
    v = src[j];
  } else {
    int j = i - 98304;                 // outw layout: lwT[col*32+row]
    v = lw[(j & 31) * 128 + (j >> 5)];
  }
  outw[i] = f2bf(v);
}

extern "C" void kernel_launch(void* const* d_in, const int* in_sizes, int n_in,
                              void* d_out, int out_size, void* d_ws, size_t ws_size,
                              hipStream_t stream) {
  short* wbf = (short*)d_ws;  // 204800 bytes used
  convert_w<<<400, 256, 0, stream>>>(
      (const float*)d_in[7], (const float*)d_in[9], (const float*)d_in[11],
      (const float*)d_in[13], (const float*)d_in[15], (const float*)d_in[17],
      (const float*)d_in[19], (const float*)d_in[21], (const float*)d_in[23], wbf);
  autoint_main<<<NSAMP / 2, 256, 0, stream>>>(
      (const int*)d_in[0], (const float*)d_in[1], (const int*)d_in[2],
      (const float*)d_in[3], (const float*)d_in[4], (const float*)d_in[5],
      (const float*)d_in[6],
      (const float*)d_in[8], (const float*)d_in[10], (const float*)d_in[12],
      (const float*)d_in[14], (const float*)d_in[16], (const float*)d_in[18],
      (const float*)d_in[20], (const float*)d_in[22], (const float*)d_in[24],
      wbf, (float*)d_out);
}

// Round 14
// 317.800 us; speedup vs baseline: 1.0114x; 1.0114x over previous
//
#include <hip/hip_runtime.h>
#include <hip/hip_bf16.h>

// AutoInt fused: embedding gather -> 2x MHSA (32 fields, 4 heads x 32) -> logit.
// R14 = R12 parallel dual-sample MFMA chains (the -17% win) + R13 packed
//   v_cvt_pk_bf16_f32 conversions (the VALU cut). R13's sequential epilogue
//   (which serialized the chains) reverted.

#define NSAMP 8192
#define S_Y1 72    // layer1 input stride (shorts)
#define S_Y2 136   // layer2 input stride (shorts)
#define S_T 36     // 32x32 tile stride (shorts)

typedef __attribute__((ext_vector_type(8))) short bf8_t;   // 8 bf16 (4 VGPRs)
typedef __attribute__((ext_vector_type(16))) float f16v;   // 32x32 C/D

__device__ __forceinline__ unsigned pk2u(float a, float b) {
  __hip_bfloat162 h = __float22bfloat162_rn(make_float2(a, b));  // RNE, packed
  unsigned u; __builtin_memcpy(&u, &h, 4); return u;             // low16 = a
}
__device__ __forceinline__ short f2bf(float f) {
  unsigned u = __float_as_uint(f);
  u += 0x7fffu + ((u >> 16) & 1u);   // RNE (scalar, convert_w only)
  return (short)(u >> 16);
}
__device__ __forceinline__ float bf2f(short s) {
  return __uint_as_float(((unsigned)(unsigned short)s) << 16);
}
__device__ __forceinline__ f16v mfma32(bf8_t a, bf8_t b, f16v c) {
  return __builtin_amdgcn_mfma_f32_32x32x16_bf16(a, b, c, 0, 0, 0);
}

// Two samples' 32x32 proj tiles sharing one set of W fragments.
template<int D>
__device__ __forceinline__ void proj2(const bf8_t (&af)[2][D / 16],
                                      const short* __restrict__ W,
                                      const float* __restrict__ bias,
                                      int n0, int col, int h2, f16v (&o)[2]) {
  float bb = bias[n0 + col];
#pragma unroll
  for (int i = 0; i < 16; ++i) { o[0][i] = bb; o[1][i] = bb; }
#pragma unroll
  for (int kc = 0; kc < D / 16; ++kc) {
    bf8_t w = *(const bf8_t*)&W[(n0 + col) * D + kc * 16 + h2 * 8];
    o[0] = mfma32(af[0][kc], w, o[0]);
    o[1] = mfma32(af[1][kc], w, o[1]);
  }
}

// One attention layer for this wave's head, BOTH samples (R12 structure).
template<int D_IN, int S_IN, bool FUSE>
__device__ void attn_layer(const short* yIn0, const short* yIn1,
                           short* yOut0, short* yOut1,
                           const short* __restrict__ Wq, const short* __restrict__ Wk,
                           const short* __restrict__ Wv, const short* __restrict__ Wr,
                           const float* __restrict__ bq, const float* __restrict__ bk,
                           const float* __restrict__ bvp, const float* __restrict__ br,
                           short* bQ0, short* bK0, short* bQ1, short* bK1,
                           const short* __restrict__ lwT,
                           int n0, int col, int h2, float (&pp)[2]) {
  constexpr int KS = D_IN / 16;
  const short* yIn[2] = {yIn0, yIn1};
  short* bQ[2] = {bQ0, bQ1};
  short* bK[2] = {bK0, bK1};

  // A-fragments for both samples
  bf8_t af[2][KS];
#pragma unroll
  for (int sp = 0; sp < 2; ++sp)
#pragma unroll
    for (int kc = 0; kc < KS; ++kc)
      af[sp][kc] = *(const bf8_t*)&yIn[sp][col * S_IN + kc * 16 + h2 * 8];
  __syncthreads();   // yIn overlays dead; tile regions writable

  f16v acc[2];

  // ---- Q -> bQ row-major (packed converts; rows r,r+1)
  proj2<D_IN>(af, Wq, bq, n0, col, h2, acc);
#pragma unroll
  for (int sp = 0; sp < 2; ++sp)
#pragma unroll
    for (int reg = 0; reg < 16; reg += 2) {
      int row = (reg & 3) + 8 * (reg >> 2) + 4 * h2;
      unsigned u = pk2u(acc[sp][reg], acc[sp][reg + 1]);
      bQ[sp][row * S_T + col] = (short)u;
      bQ[sp][(row + 1) * S_T + col] = (short)(u >> 16);
    }

  // ---- K -> bK row-major
  proj2<D_IN>(af, Wk, bk, n0, col, h2, acc);
#pragma unroll
  for (int sp = 0; sp < 2; ++sp)
#pragma unroll
    for (int reg = 0; reg < 16; reg += 2) {
      int row = (reg & 3) + 8 * (reg >> 2) + 4 * h2;
      unsigned u = pk2u(acc[sp][reg], acc[sp][reg + 1]);
      bK[sp][row * S_T + col] = (short)u;
      bK[sp][(row + 1) * S_T + col] = (short)(u >> 16);
    }

  // ---- Res -> registers (C-layout, aligned with PV output)
  f16v res[2];
  proj2<D_IN>(af, Wr, br, n0, col, h2, res);

  // ---- scores = Q K^T (both samples interleaved); e = exp(z) -> bQ
  {
    f16v z[2];
#pragma unroll
    for (int sp = 0; sp < 2; ++sp)
#pragma unroll
      for (int i = 0; i < 16; ++i) z[sp][i] = 0.f;
#pragma unroll
    for (int kc = 0; kc < 2; ++kc) {
#pragma unroll
      for (int sp = 0; sp < 2; ++sp) {
        bf8_t qa = *(const bf8_t*)&bQ[sp][col * S_T + kc * 16 + h2 * 8];
        bf8_t kb = *(const bf8_t*)&bK[sp][col * S_T + kc * 16 + h2 * 8];
        z[sp] = mfma32(qa, kb, z[sp]);
      }
    }
#pragma unroll
    for (int sp = 0; sp < 2; ++sp)
#pragma unroll
      for (int reg = 0; reg < 16; reg += 2) {
        int row = (reg & 3) + 8 * (reg >> 2) + 4 * h2;
        unsigned u = pk2u(__expf(z[sp][reg]), __expf(z[sp][reg + 1]));
        bQ[sp][row * S_T + col] = (short)u;
        bQ[sp][(row + 1) * S_T + col] = (short)(u >> 16);
      }
  }

  // ---- V -> bK transposed (both samples); packed 8B stores
  proj2<D_IN>(af, Wv, bvp, n0, col, h2, acc);
#pragma unroll
  for (int sp = 0; sp < 2; ++sp)
#pragma unroll
    for (int g = 0; g < 4; ++g) {
      uint2 w;
      w.x = pk2u(acc[sp][g * 4 + 0], acc[sp][g * 4 + 1]);
      w.y = pk2u(acc[sp][g * 4 + 2], acc[sp][g * 4 + 3]);
      *(uint2*)&bK[sp][col * S_T + 8 * g + 4 * h2] = w;
    }

  // ---- PV + row-sums via all-ones B-frag, PARALLEL dual chains (R12)
  const short onebf = (short)0x3F80;
  bf8_t ones = {onebf, onebf, onebf, onebf, onebf, onebf, onebf, onebf};
  f16v pv[2], sums[2];
#pragma unroll
  for (int sp = 0; sp < 2; ++sp)
#pragma unroll
    for (int i = 0; i < 16; ++i) { pv[sp][i] = 0.f; sums[sp][i] = 0.f; }
#pragma unroll
  for (int kc = 0; kc < 2; ++kc) {
#pragma unroll
    for (int sp = 0; sp < 2; ++sp) {
      bf8_t pa = *(const bf8_t*)&bQ[sp][col * S_T + kc * 16 + h2 * 8];
      bf8_t vb = *(const bf8_t*)&bK[sp][col * S_T + kc * 16 + h2 * 8];
      pv[sp] = mfma32(pa, vb, pv[sp]);
      sums[sp] = mfma32(pa, ones, sums[sp]);
    }
  }

  if (FUSE) {
#pragma unroll
    for (int g = 0; g < 4; ++g) {
      short4 l4 = *(const short4*)&lwT[(n0 + col) * 32 + 8 * g + 4 * h2];
#pragma unroll
      for (int r = 0; r < 4; ++r) {
        int reg = g * 4 + r;
        float lw = bf2f((r == 0) ? l4.x : (r == 1) ? l4.y : (r == 2) ? l4.z : l4.w);
        pp[0] += fmaxf(fmaf(pv[0][reg], 1.f / sums[0][reg], res[0][reg]), 0.f) * lw;
        pp[1] += fmaxf(fmaf(pv[1][reg], 1.f / sums[1][reg], res[1][reg]), 0.f) * lw;
      }
    }
  } else {
    __syncthreads();   // all waves done reading tiles; regions writable as yOut
    short* yOut[2] = {yOut0, yOut1};
#pragma unroll
    for (int sp = 0; sp < 2; ++sp)
#pragma unroll
      for (int reg = 0; reg < 16; reg += 2) {
        int row = (reg & 3) + 8 * (reg >> 2) + 4 * h2;
        float o0 = fmaxf(fmaf(pv[sp][reg], 1.f / sums[sp][reg], res[sp][reg]), 0.f);
        float o1 = fmaxf(fmaf(pv[sp][reg + 1], 1.f / sums[sp][reg + 1],
                              res[sp][reg + 1]), 0.f);
        unsigned u = pk2u(o0, o1);
        yOut[sp][row * S_Y2 + n0 + col] = (short)u;
        yOut[sp][(row + 1) * S_Y2 + n0 + col] = (short)(u >> 16);
      }
  }
}

__global__ __launch_bounds__(256, 3) void autoint_main(
    const int* __restrict__ onehot_i, const float* __restrict__ onehot_x,
    const int* __restrict__ mh_i, const float* __restrict__ mh_x,
    const float* __restrict__ ctns, const float* __restrict__ xx,
    const float* __restrict__ xy,
    const float* __restrict__ bq1, const float* __restrict__ bk1,
    const float* __restrict__ bv1, const float* __restrict__ br1,
    const float* __restrict__ bq2, const float* __restrict__ bk2,
    const float* __restrict__ bv2, const float* __restrict__ br2,
    const float* __restrict__ logitb, const short* __restrict__ wbf,
    float* __restrict__ out) {
  // Per-sample 18432B region (8 head-tiles) hosting y1 (4608B) / y2 (8704B)
  // overlays at its base, lifetimes fenced by barriers. Two samples/block.
  __shared__ __align__(16) short scr[2][9216];
  __shared__ float red[4][2];

  const int t = threadIdx.x;
  const int head = t >> 6;
  const int lane = t & 63;
  const int col = lane & 31;
  const int h2 = lane >> 5;
  const int n0 = head * 32;
  const int s0 = blockIdx.x * 2;

  short* bQ0 = &scr[0][(head * 2 + 0) * 1152];
  short* bK0 = &scr[0][(head * 2 + 1) * 1152];
  short* bQ1 = &scr[1][(head * 2 + 0) * 1152];
  short* bK1 = &scr[1][(head * 2 + 1) * 1152];

  // ---- embedding build: both samples' y1, all 256 threads each
#pragma unroll
  for (int se = 0; se < 2; ++se) {
    const int sg = s0 + se;
    short* yA = &scr[se][0];
    for (int idx = t; idx < 320; idx += 256) {     // 20 onehot x 16 float4
      int f = idx >> 4, e4 = idx & 15;
      int row = onehot_i[sg * 20 + f];
      float xw = onehot_x[sg * 20 + f];
      float4 xv = *(const float4*)&xx[row * 64 + e4 * 4];
      uint2 w; w.x = pk2u(xv.x * xw, xv.y * xw); w.y = pk2u(xv.z * xw, xv.w * xw);
      *(uint2*)&yA[f * S_Y1 + e4 * 4] = w;
    }
    {                                               // 2 multihot x 16 float4, 8-way k-split
      int slot = t >> 3, ks = t & 7;
      int j = slot >> 4, e4 = slot & 15;
      const int* ip = &mh_i[(j * NSAMP + sg) * 50];
      const float* xp = &mh_x[(j * NSAMP + sg) * 50];
      float a0 = 0.f, a1 = 0.f, a2 = 0.f, a3 = 0.f;
      for (int k = ks; k < 50; k += 8) {
        float4 xv = *(const float4*)&xx[ip[k] * 64 + e4 * 4];
        float w = xp[k];
        a0 += xv.x * w; a1 += xv.y * w; a2 += xv.z * w; a3 += xv.w * w;
      }
#pragma unroll
      for (int d = 1; d < 8; d <<= 1) {
        a0 += __shfl_xor(a0, d); a1 += __shfl_xor(a1, d);
        a2 += __shfl_xor(a2, d); a3 += __shfl_xor(a3, d);
      }
      if (ks == 0) {
        uint2 w; w.x = pk2u(a0, a1); w.y = pk2u(a2, a3);
        *(uint2*)&yA[(20 + j) * S_Y1 + e4 * 4] = w;
      }
    }
    if (t < 160) {                                  // 10 ctns x 16 float4
      int ci = t >> 4, e4 = t & 15;
      float cv = ctns[sg * 10 + ci];
      float4 xv = *(const float4*)&xy[ci * 64 + e4 * 4];
      uint2 w; w.x = pk2u(cv * xv.x, cv * xv.y); w.y = pk2u(cv * xv.z, cv * xv.w);
      *(uint2*)&yA[(22 + ci) * S_Y1 + e4 * 4] = w;
    }
  }
  __syncthreads();

  float pp[2] = {0.f, 0.f};
  attn_layer<64, S_Y1, false>(&scr[0][0], &scr[1][0], &scr[0][0], &scr[1][0],
      wbf + 0, wbf + 8192, wbf + 16384, wbf + 24576,
      bq1, bk1, bv1, br1, bQ0, bK0, bQ1, bK1, nullptr, n0, col, h2, pp);
  __syncthreads();   // y2 fully written before layer2 frag load
  attn_layer<128, S_Y2, true>(&scr[0][0], &scr[1][0], nullptr, nullptr,
      wbf + 32768, wbf + 49152, wbf + 65536, wbf + 81920,
      bq2, bk2, bv2, br2, bQ0, bK0, bQ1, bK1, wbf + 98304, n0, col, h2, pp);

  // ---- logit partials: wave-reduce each sample, combine heads
#pragma unroll
  for (int off = 32; off > 0; off >>= 1) {
    pp[0] += __shfl_xor(pp[0], off);
    pp[1] += __shfl_xor(pp[1], off);
  }
  if (lane == 0) { red[head][0] = pp[0]; red[head][1] = pp[1]; }
  __syncthreads();
  if (t < 2) {
    float zz = red[0][t] + red[1][t] + red[2][t] + red[3][t] + logitb[0];
    out[s0 + t] = 1.f / (1.f + __expf(-zz));
  }
}

// fp32 -> bf16 weight conversion into ws:
// [0)QW1 [8192)KW1 [16384)VW1 [24576)RW1 [32768)QW2 [49152)KW2 [65536)VW2
// [81920)RW2 [98304)logitW TRANSPOSED [128][32]
__global__ void convert_w(const float* __restrict__ qw1, const float* __restrict__ kw1,
                          const float* __restrict__ vw1, const float* __restrict__ rw1,
                          const float* __restrict__ qw2, const float* __restrict__ kw2,
                          const float* __restrict__ vw2, const float* __restrict__ rw2,
                          const float* __restrict__ lw, short* __restrict__ outw) {
  int i = blockIdx.x * 256 + threadIdx.x;
  if (i >= 102400) return;
  float v;
  if (i < 32768) {
    int tsel = i >> 13, j = i & 8191;
    const float* src = tsel == 0 ? qw1 : tsel == 1 ? kw1 : tsel == 2 ? vw1 : rw1;
    v = src[j];
  } else if (i < 98304) {
    int k = i - 32768;
    int tsel = k >> 14, j = k & 16383;
    const float* src = tsel == 0 ? qw2 : tsel == 1 ? kw2 : tsel == 2 ? vw2 : rw2;
    v = src[j];
  } else {
    int j = i - 98304;                 // outw layout: lwT[col*32+row]
    v = lw[(j & 31) * 128 + (j >> 5)];
  }
  outw[i] = f2bf(v);
}

extern "C" void kernel_launch(void* const* d_in, const int* in_sizes, int n_in,
                              void* d_out, int out_size, void* d_ws, size_t ws_size,
                              hipStream_t stream) {
  short* wbf = (short*)d_ws;  // 204800 bytes used
  convert_w<<<400, 256, 0, stream>>>(
      (const float*)d_in[7], (const float*)d_in[9], (const float*)d_in[11],
      (const float*)d_in[13], (const float*)d_in[15], (const float*)d_in[17],
      (const float*)d_in[19], (const float*)d_in[21], (const float*)d_in[23], wbf);
  autoint_main<<<NSAMP / 2, 256, 0, stream>>>(
      (const int*)d_in[0], (const float*)d_in[1], (const int*)d_in[2],
      (const float*)d_in[3], (const float*)d_in[4], (const float*)d_in[5],
      (const float*)d_in[6],
      (const float*)d_in[8], (const float*)d_in[10], (const float*)d_in[12],
      (const float*)d_in[14], (const float*)d_in[16], (const float*)d_in[18],
      (const float*)d_in[20], (const float*)d_in[22], (const float*)d_in[24],
      wbf, (float*)d_out);
}